// Round 8
// baseline (279.114 us; speedup 1.0000x reference)
//
#include <hip/hip_runtime.h>
#include <math.h>

typedef __attribute__((ext_vector_type(8))) short bf16x8;
typedef __attribute__((ext_vector_type(4))) float f32x4;

#define DEV __device__ __forceinline__

DEV unsigned short f2b(float f) {
    union { float f; unsigned u; } x;
    x.f = f;
    unsigned r = x.u + 0x7fff + ((x.u >> 16) & 1);  // RNE
    return (unsigned short)(r >> 16);
}
DEV float b2f(unsigned short u) {
    union { unsigned u; float f; } x;
    x.u = ((unsigned)u) << 16;
    return x.f;
}

// async global->LDS, 16B per lane; LDS dest must be wave-uniform base + lane*16
DEV void glds16(const void* g, void* l) {
    __builtin_amdgcn_global_load_lds(
        (const __attribute__((address_space(1))) void*)g,
        (__attribute__((address_space(3))) void*)l, 16, 0, 0);
}

// ---------------------------------------------------------------------------
// P0: fused prologue — one launch, three block-uniform jobs co-running:
//   id <  4096: X fp32 -> bf16            (Xb)
//   id <  4864: Wqkv fp32 -> W^T bf16     (Wt,  N=3072, 48x16 tiles)
//   else      : Wout fp32 -> W^T bf16     (Wt2, N=1024, 16x16 tiles)
// ---------------------------------------------------------------------------
__global__ __launch_bounds__(256) void prep_kern(
    const float* __restrict__ x,    unsigned short* __restrict__ Xb,
    const float* __restrict__ Wqkv, unsigned short* __restrict__ Wt,
    const float* __restrict__ Wout, unsigned short* __restrict__ Wt2)
{
    __shared__ short S[64 * 65];
    const int id = blockIdx.x, tid = threadIdx.x;

    if (id < 4096) {
        int i = (id * 256 + tid) * 8;
        float4 a = *(const float4*)(x + i);
        float4 b = *(const float4*)(x + i + 4);
        int4 tv;
        short* tp = reinterpret_cast<short*>(&tv);
        tp[0] = (short)f2b(a.x); tp[1] = (short)f2b(a.y);
        tp[2] = (short)f2b(a.z); tp[3] = (short)f2b(a.w);
        tp[4] = (short)f2b(b.x); tp[5] = (short)f2b(b.y);
        tp[6] = (short)f2b(b.z); tp[7] = (short)f2b(b.w);
        *(int4*)(Xb + i) = tv;
        return;
    }

    const float* W;
    unsigned short* Wo;
    int N, n0, k0;
    if (id < 4864) {
        int t = id - 4096;                       // 768 tiles: 48 x 16
        W = Wqkv; Wo = Wt; N = 3072;
        n0 = (t % 48) * 64; k0 = (t / 48) * 64;
    } else {
        int t = id - 4864;                       // 256 tiles: 16 x 16
        W = Wout; Wo = Wt2; N = 1024;
        n0 = (t % 16) * 64; k0 = (t / 16) * 64;
    }
#pragma unroll
    for (int p = 0; p < 16; p++) {
        int idx = p * 256 + tid;
        int r = idx >> 6, c = idx & 63;          // r = k, c = n (coalesced read)
        S[c * 65 + r] = (short)f2b(W[(size_t)(k0 + r) * N + n0 + c]);
    }
    __syncthreads();
#pragma unroll
    for (int p = 0; p < 8; p++) {
        int idx = p * 256 + tid;
        int r = idx >> 5, cp = (idx & 31) * 2;   // r = n, cp = k pair
        unsigned lo = (unsigned short)S[r * 65 + cp];
        unsigned hi = (unsigned short)S[r * 65 + cp + 1];
        *(unsigned*)(Wo + (size_t)(n0 + r) * 1024 + k0 + cp) = lo | (hi << 16);
    }
}

// ---------------------------------------------------------------------------
// K1: QKV GEMM (all bf16). C[8192,3072] = Xb @ Wt^T + b
// 256x128 tile, BK=64, 512 threads (8 waves, 4Mx2N), 48 KB LDS.
// NO launch-bounds min-wave clamp (round 4's spill cause: (512,4) capped
// VGPR at 128 -> scratch traffic +100 MB; this isolates the tile-shape test).
// Staged bytes per MFMA-FLOP -25% vs 128x128; acc[4][4]/wave unchanged.
//  * XOR-swizzled LDS (verified: conflicts -24x)
//  * blob epilogue in two 128-row halves (verified round 4 correctness)
// XCD-chunked remap: 768 blocks, 96/XCD = 4 m-tiles x 24 n-tiles
// (A-panel 2 MB, L2-resident). Grid 768 = exactly 3 blocks/CU, zero tail.
//   Kf[bh][kt(8)][kk(2)][j(8)][lane(64)][t(8)]
//   Vf[bh][kt(8)][kk2(4)][jo(4)][lane(64)][t(8)]
// ---------------------------------------------------------------------------
__global__ __launch_bounds__(512) void qkv_gemm(
    const unsigned short* __restrict__ Xb,   // [8192][1024] bf16
    const unsigned short* __restrict__ Wt,   // [3072][1024] bf16 = W^T
    const float* __restrict__ bq,
    unsigned short* __restrict__ Qb,
    unsigned short* __restrict__ Kf,
    unsigned short* __restrict__ Vf)
{
    __shared__ __align__(16) short As[256 * 64];   // 32 KB (also epilogue buf)
    __shared__ __align__(16) short Bs[128 * 64];   // 16 KB

    // XCD-chunked remap: 768 blocks, 96 per XCD = 4 row-tiles x 24 col-tiles
    const int flat = blockIdx.y * 24 + blockIdx.x;
    const int xcd = flat & 7, local = flat >> 3;
    const int m0 = (xcd * 4 + local / 24) * 256;
    const int n0 = (local % 24) * 128;

    const int tid = threadIdx.x;
    const int wave = tid >> 6, lane = tid & 63;
    const int quad = lane >> 4, lcol = lane & 15;
    const int wr = wave >> 1, wc = wave & 1;
    const int wrow = wr * 64, wcol = wc * 64;

    f32x4 acc[4][4];
#pragma unroll
    for (int i = 0; i < 4; i++)
#pragma unroll
        for (int j = 0; j < 4; j++) acc[i][j] = (f32x4){0.f, 0.f, 0.f, 0.f};

    const int sr = tid >> 3;                 // 0..63: row within 64-row pass
    const int g_lin = tid & 7;               // linear dest granule (8 shorts)
    const int g_src = g_lin ^ (sr & 7);      // pre-swizzled source granule
    const int swz = lcol & 7;                // read-side XOR

    for (int k0 = 0; k0 < 1024; k0 += 64) {
        __syncthreads();
#pragma unroll
        for (int p = 0; p < 4; p++)
            glds16(Xb + (size_t)(m0 + p * 64 + sr) * 1024 + k0 + g_src * 8,
                   &As[(p * 64 + sr) * 64 + g_lin * 8]);
#pragma unroll
        for (int p = 0; p < 2; p++)
            glds16(Wt + (size_t)(n0 + p * 64 + sr) * 1024 + k0 + g_src * 8,
                   &Bs[(p * 64 + sr) * 64 + g_lin * 8]);
        __syncthreads();
#pragma unroll
        for (int kk = 0; kk < 2; kk++) {
            bf16x8 a[4], b[4];
#pragma unroll
            for (int i = 0; i < 4; i++)
                a[i] = *(const bf16x8*)(&As[(wrow + 16 * i + lcol) * 64
                                            + ((kk * 4 + quad) ^ swz) * 8]);
#pragma unroll
            for (int j = 0; j < 4; j++)
                b[j] = *(const bf16x8*)(&Bs[(wcol + 16 * j + lcol) * 64
                                            + ((kk * 4 + quad) ^ swz) * 8]);
#pragma unroll
            for (int i = 0; i < 4; i++)
#pragma unroll
                for (int j = 0; j < 4; j++)
                    acc[i][j] = __builtin_amdgcn_mfma_f32_16x16x32_bf16(
                        a[i], b[j], acc[i][j], 0, 0, 0);
        }
    }
    __syncthreads();   // all ds_reads done before reusing As as epilogue buf

    // ---- epilogue: two 128-row halves; stage into Es in blob order ----
    short* Es = As;                          // 32 KB = one 128x128 half-tile
    const int which = n0 >> 10;              // 0=Q 1=K 2=V (tile-uniform)
    const int h0 = (n0 & 1023) >> 6;
    const int bb = m0 >> 10;
    const int sl0 = m0 & 1023;

#pragma unroll
    for (int hh = 0; hh < 2; hh++) {
        if ((wr >> 1) == hh) {               // waves owning this 128-row half
#pragma unroll
            for (int j = 0; j < 4; j++) {
                int colt = wcol + 16 * j + lcol;          // 0..127
                float bias = bq[n0 + colt];
                int g = colt >> 6, e = colt & 63;
#pragma unroll
                for (int i = 0; i < 4; i++) {
#pragma unroll
                    for (int reg = 0; reg < 4; reg++) {
                        int ls = (wr & 1) * 64 + 16 * i + quad * 4 + reg; // 0..127
                        unsigned short v = f2b(acc[i][j][reg] + bias);
                        int off;
                        if (which == 0)
                            off = ls * 64 + e;
                        else if (which == 1)
                            off = (e >> 5) * 4096 + (ls >> 4) * 512
                                + (((e >> 3) & 3) * 16 + (ls & 15)) * 8 + (e & 7);
                        else
                            off = (ls >> 5) * 2048 + (e >> 4) * 512
                                + ((((ls >> 3) & 3) * 16) + (e & 15)) * 8 + (ls & 7);
                        Es[g * 8192 + off] = (short)v;
                    }
                }
            }
        }
        __syncthreads();
        // copy out 32 KB: two 16 KB blobs (heads h0, h0+1)
        const int kt = (sl0 >> 7) + hh;
#pragma unroll
        for (int rd = 0; rd < 4; rd++) {
            int fl = rd * 4096 + tid * 8;
            int g = fl >> 13, off = fl & 8191;
            bf16x8 val = *(const bf16x8*)(&Es[fl]);
            int bh = bb * 16 + h0 + g;
            if (which == 0)
                *(bf16x8*)(Qb + ((size_t)bh * 1024 + sl0 + hh * 128) * 64 + off) = val;
            else if (which == 1)
                *(bf16x8*)(Kf + ((size_t)bh * 8 + kt) * 8192 + off) = val;
            else
                *(bf16x8*)(Vf + ((size_t)bh * 8 + kt) * 8192 + off) = val;
        }
        if (hh == 0) __syncthreads();        // Es reused by second half
    }
}

// ---------------------------------------------------------------------------
// K2: causal flash attention — EQUAL-WORK blocks + SWAPPED-OPERAND QK^T
// + T5 s_setprio around MFMA clusters (round-7 verified best).
// ---------------------------------------------------------------------------
__global__ __launch_bounds__(256, 4) void attn_kern(
    const unsigned short* __restrict__ Qb,
    const unsigned short* __restrict__ Kf,
    const unsigned short* __restrict__ Vf,
    unsigned short* __restrict__ Ob)
{
    __shared__ __align__(16) short Ps[64 * 136];    // 17.4 KB, wave-private slices

    const int xb = blockIdx.x;                      // 0..7
    const int bh = blockIdx.y;                      // 0..127
    const int pr = xb >> 1;                         // pair 0..3
    const int hf = xb & 1;                          // half-strip 0..1
    const unsigned short* Qp = Qb + (size_t)bh * 65536;
    const unsigned short* Kp = Kf + (size_t)bh * 65536;
    const unsigned short* Vp = Vf + (size_t)bh * 65536;

    const int tid = threadIdx.x;
    const int wave = tid >> 6, lane = tid & 63;
    const int quad = lane >> 4, lcol = lane & 15;
    const int hw4 = hf * 4 + wave;                  // 0..7: 16-row strip in tile
    const int qloc = hw4 * 16 + lcol;               // lane's q within its tile

    const float sc2 = 0.0450711882f;  // log2(e)/32  (scale folded into exp2)
    const int b = bh >> 4, h = bh & 15;

    for (int pass = 0; pass < 2; pass++) {
        const int qt = pass ? (7 - pr) : pr;        // q-tile index 0..7
        const int q0 = qt * 128 + hf * 64 + wave * 16;  // wave's first q row

        // Q fragments (B-operand: q=lane&15, k=quad*8+t)
        bf16x8 qa[2];
#pragma unroll
        for (int kk = 0; kk < 2; kk++)
            qa[kk] = *(const bf16x8*)(Qp + (size_t)(q0 + lcol) * 64
                                      + kk * 32 + quad * 8);

        f32x4 o_acc[4];
#pragma unroll
        for (int jo = 0; jo < 4; jo++) o_acc[jo] = (f32x4){0.f, 0.f, 0.f, 0.f};
        float l_loc = 0.f;

        for (int kt = 0; kt <= qt; kt++) {
            const bool diag = (kt == qt);
            const int jmax = diag ? hw4 : 7;        // max live 16-key tile
            const int kk2max = diag ? (hw4 >> 1) : 3;

            // S^T = K Q^T : lane holds S^T[key=16j+quad*4+reg][q=lcol]
            f32x4 scT[8];
#pragma unroll
            for (int j = 0; j < 8; j++) scT[j] = (f32x4){0.f, 0.f, 0.f, 0.f};
#pragma unroll
            for (int kk = 0; kk < 2; kk++) {
                bf16x8 kb[8];
#pragma unroll
                for (int j = 0; j < 8; j++)
                    if (j <= jmax)
                        kb[j] = *(const bf16x8*)(Kp
                            + ((size_t)((kt * 2 + kk) * 8 + j) << 9) + lane * 8);
                __builtin_amdgcn_s_setprio(1);
#pragma unroll
                for (int j = 0; j < 8; j++)
                    if (j <= jmax)
                        scT[j] = __builtin_amdgcn_mfma_f32_16x16x32_bf16(
                            kb[j], qa[kk], scT[j], 0, 0, 0);
                __builtin_amdgcn_s_setprio(0);
            }

            // max-free softmax; packed b64 store to Ps[q][key]
#pragma unroll
            for (int j = 0; j < 8; j++) {
                if (j <= jmax) {
                    float pv[4];
#pragma unroll
                    for (int r = 0; r < 4; r++) {
                        float p = exp2f(scT[j][r] * sc2);
                        if (diag && (16 * j + quad * 4 + r) > qloc) p = 0.f;
                        l_loc += p;
                        pv[r] = p;
                    }
                    ushort4 pk;
                    pk.x = f2b(pv[0]); pk.y = f2b(pv[1]);
                    pk.z = f2b(pv[2]); pk.w = f2b(pv[3]);
                    *(ushort4*)(&Ps[(wave * 16 + lcol) * 136 + 16 * j + quad * 4]) = pk;
                }
            }
            // diag with even jmax: PV's kk2max chunk reads tile jmax+1 -> zero it
            if (diag && !(jmax & 1)) {
                *(ushort4*)(&Ps[(wave * 16 + lcol) * 136 + 16 * (jmax + 1) + quad * 4]) =
                    (ushort4){0, 0, 0, 0};
            }

            // O += P @ V  (pa: A-layout b128 read of own rows; vb: 1 KB loads)
#pragma unroll
            for (int kk2 = 0; kk2 < 4; kk2++) {
                if (kk2 <= kk2max) {
                    bf16x8 pa = *(const bf16x8*)(&Ps[(wave * 16 + lcol) * 136
                                                     + kk2 * 32 + quad * 8]);
                    bf16x8 vb[4];
#pragma unroll
                    for (int jo = 0; jo < 4; jo++)
                        vb[jo] = *(const bf16x8*)(Vp
                            + ((size_t)((kt * 4 + kk2) * 4 + jo) << 9) + lane * 8);
                    __builtin_amdgcn_s_setprio(1);
#pragma unroll
                    for (int jo = 0; jo < 4; jo++)
                        o_acc[jo] = __builtin_amdgcn_mfma_f32_16x16x32_bf16(
                            pa, vb[jo], o_acc[jo], 0, 0, 0);
                    __builtin_amdgcn_s_setprio(0);
                }
            }
        }

        // l: sum the 4 quads (lanes with equal lcol hold the same q)
        l_loc += __shfl_xor(l_loc, 16);
        l_loc += __shfl_xor(l_loc, 32);
        float inv = 1.0f / l_loc;                   // inv for q = q0 + lcol
        float invq[4];
#pragma unroll
        for (int r = 0; r < 4; r++) invq[r] = __shfl(inv, quad * 4 + r);

        // write O -> [B, S, H*hd] bf16  (C-layout: row=q=quad*4+reg, col=d=16jo+lcol)
#pragma unroll
        for (int jo = 0; jo < 4; jo++) {
#pragma unroll
            for (int r = 0; r < 4; r++) {
                int q = q0 + quad * 4 + r;
                Ob[(size_t)(b * 1024 + q) * 1024 + h * 64 + 16 * jo + lcol] =
                    f2b(o_acc[jo][r] * invq[r]);
            }
        }
        l_loc = 0.f;
    }
}

// ---------------------------------------------------------------------------
// K3: out proj. P2[8192,1024](bf16) = O @ Wout + bout + X(fp32 residual)
// 128x128 tile + XOR-swizzled LDS + XCD-chunked remap (round-5 verified).
// ---------------------------------------------------------------------------
__global__ __launch_bounds__(256) void out_gemm(
    const unsigned short* __restrict__ O,
    const unsigned short* __restrict__ Wt2,  // [1024][1024] bf16 = Wout^T
    const float* __restrict__ bo,
    const float* __restrict__ X,
    unsigned short* __restrict__ P2)
{
    __shared__ __align__(16) short As[128 * 64];
    __shared__ __align__(16) short Bs[128 * 64];

    // XCD-chunked remap: 512 blocks, 64 per XCD = 8 row-tiles x 8 col-tiles
    const int flat = blockIdx.y * 8 + blockIdx.x;
    const int xcd = flat & 7, local = flat >> 3;
    const int m0 = (xcd * 8 + (local >> 3)) * 128;
    const int n0 = (local & 7) * 128;

    const int tid = threadIdx.x;
    const int wave = tid >> 6, lane = tid & 63;
    const int quad = lane >> 4, lcol = lane & 15;
    const int wrow = (wave >> 1) * 64, wcol = (wave & 1) * 64;

    f32x4 acc[4][4];
#pragma unroll
    for (int i = 0; i < 4; i++)
#pragma unroll
        for (int j = 0; j < 4; j++) acc[i][j] = (f32x4){0.f, 0.f, 0.f, 0.f};

    const int sr = tid >> 3;                 // 0..31
    const int g_lin = tid & 7;
    const int g_src = g_lin ^ (sr & 7);
    const int swz = lcol & 7;

    for (int k0 = 0; k0 < 1024; k0 += 64) {
        __syncthreads();
#pragma unroll
        for (int p = 0; p < 4; p++) {
            glds16(O + (size_t)(m0 + p * 32 + sr) * 1024 + k0 + g_src * 8,
                   &As[(p * 32 + sr) * 64 + g_lin * 8]);
            glds16(Wt2 + (size_t)(n0 + p * 32 + sr) * 1024 + k0 + g_src * 8,
                   &Bs[(p * 32 + sr) * 64 + g_lin * 8]);
        }
        __syncthreads();
#pragma unroll
        for (int kk = 0; kk < 2; kk++) {
            bf16x8 a[4], b[4];
#pragma unroll
            for (int i = 0; i < 4; i++)
                a[i] = *(const bf16x8*)(&As[(wrow + 16 * i + lcol) * 64
                                            + ((kk * 4 + quad) ^ swz) * 8]);
#pragma unroll
            for (int j = 0; j < 4; j++)
                b[j] = *(const bf16x8*)(&Bs[(wcol + 16 * j + lcol) * 64
                                            + ((kk * 4 + quad) ^ swz) * 8]);
#pragma unroll
            for (int i = 0; i < 4; i++)
#pragma unroll
                for (int j = 0; j < 4; j++)
                    acc[i][j] = __builtin_amdgcn_mfma_f32_16x16x32_bf16(
                        a[i], b[j], acc[i][j], 0, 0, 0);
        }
    }

#pragma unroll
    for (int j = 0; j < 4; j++) {
        int c = n0 + wcol + 16 * j + lcol;
        float bias = bo[c];
#pragma unroll
        for (int i = 0; i < 4; i++) {
#pragma unroll
            for (int reg = 0; reg < 4; reg++) {
                int r = m0 + wrow + 16 * i + quad * 4 + reg;
                float v = acc[i][j][reg] + bias + X[(size_t)r * 1024 + c];
                P2[(size_t)r * 1024 + c] = f2b(v);
            }
        }
    }
}

// ---------------------------------------------------------------------------
// K4: LayerNorm over last dim (1024), bf16 in / fp32 out, one block per row
// ---------------------------------------------------------------------------
__global__ __launch_bounds__(256) void ln_kern(
    const unsigned short* __restrict__ P2,
    const float* __restrict__ G,
    const float* __restrict__ Bt,
    float* __restrict__ out)
{
    const int row = blockIdx.x, tid = threadIdx.x;
    const size_t base = (size_t)row * 1024 + tid * 4;

    int2 raw = *(const int2*)(P2 + base);
    float v[4];
    v[0] = b2f((unsigned short)(raw.x & 0xffff));
    v[1] = b2f((unsigned short)((unsigned)raw.x >> 16));
    v[2] = b2f((unsigned short)(raw.y & 0xffff));
    v[3] = b2f((unsigned short)((unsigned)raw.y >> 16));

    float sum = v[0] + v[1] + v[2] + v[3];
    float sq = v[0] * v[0] + v[1] * v[1] + v[2] * v[2] + v[3] * v[3];
#pragma unroll
    for (int m = 1; m < 64; m <<= 1) {
        sum += __shfl_xor(sum, m);
        sq += __shfl_xor(sq, m);
    }
    __shared__ float rs[4], rq[4];
    const int wave = tid >> 6, lane = tid & 63;
    if (lane == 0) { rs[wave] = sum; rq[wave] = sq; }
    __syncthreads();
    sum = rs[0] + rs[1] + rs[2] + rs[3];
    sq = rq[0] + rq[1] + rq[2] + rq[3];

    float mean = sum * (1.0f / 1024.0f);
    float var = fmaxf(sq * (1.0f / 1024.0f) - mean * mean, 0.0f);
    float rstd = rsqrtf(var + 1e-5f);

    float4 g = *(const float4*)(G + tid * 4);
    float4 be = *(const float4*)(Bt + tid * 4);

    float4 o;
    o.x = (v[0] - mean) * rstd * g.x + be.x;
    o.y = (v[1] - mean) * rstd * g.y + be.y;
    o.z = (v[2] - mean) * rstd * g.z + be.z;
    o.w = (v[3] - mean) * rstd * g.w + be.w;
    *(float4*)(out + base) = o;
}

// ---------------------------------------------------------------------------
// Buffer plan:
//   d_out (32 MB): Qb bf16 @0, Ob bf16 @16M; final fp32 result overwrites.
//   d_ws  (56 MB): Kf @0, Vf @16M, Wt2 @32M (2M), Xb @34M (16M), Wt @50M (6M)
//   P2 bf16 @34M aliases Xb (dead after qkv_gemm).
// ---------------------------------------------------------------------------
extern "C" void kernel_launch(void* const* d_in, const int* in_sizes, int n_in,
                              void* d_out, int out_size, void* d_ws, size_t ws_size,
                              hipStream_t stream) {
    const float* x    = (const float*)d_in[0];
    const float* Wqkv = (const float*)d_in[1];
    const float* bqkv = (const float*)d_in[2];
    const float* Wout = (const float*)d_in[3];
    const float* bout = (const float*)d_in[4];
    const float* gam  = (const float*)d_in[5];
    const float* bet  = (const float*)d_in[6];
    float* out = (float*)d_out;

    char* ws = (char*)d_ws;
    const size_t MB = (size_t)1024 * 1024;

    unsigned short* Qb  = (unsigned short*)d_out;
    unsigned short* Ob  = (unsigned short*)d_out + 8388608;
    unsigned short* Kf  = (unsigned short*)(ws);
    unsigned short* Vf  = (unsigned short*)(ws + 16 * MB);
    unsigned short* Wt2 = (unsigned short*)(ws + 32 * MB);
    unsigned short* Xb  = (unsigned short*)(ws + 34 * MB);
    unsigned short* Wt  = (unsigned short*)(ws + 50 * MB);
    unsigned short* P2  = (unsigned short*)(ws + 34 * MB);   // alias Xb

    prep_kern<<<5120, 256, 0, stream>>>(x, Xb, Wqkv, Wt, Wout, Wt2);
    qkv_gemm<<<dim3(24, 32), 512, 0, stream>>>(Xb, Wt, bqkv, Qb, Kf, Vf);
    attn_kern<<<dim3(8, 128), 256, 0, stream>>>(Qb, Kf, Vf, Ob);
    out_gemm<<<dim3(8, 64), 256, 0, stream>>>(Ob, Wt2, bout, x, P2);
    ln_kern<<<8192, 256, 0, stream>>>(P2, gam, bet, out);
}

// Round 9
// 264.785 us; speedup vs baseline: 1.0541x; 1.0541x over previous
//
#include <hip/hip_runtime.h>
#include <math.h>

typedef __attribute__((ext_vector_type(8))) short bf16x8;
typedef __attribute__((ext_vector_type(4))) float f32x4;

#define DEV __device__ __forceinline__

DEV unsigned short f2b(float f) {
    union { float f; unsigned u; } x;
    x.f = f;
    unsigned r = x.u + 0x7fff + ((x.u >> 16) & 1);  // RNE
    return (unsigned short)(r >> 16);
}
DEV float b2f(unsigned short u) {
    union { unsigned u; float f; } x;
    x.u = ((unsigned)u) << 16;
    return x.f;
}

// async global->LDS, 16B per lane; LDS dest must be wave-uniform base + lane*16
DEV void glds16(const void* g, void* l) {
    __builtin_amdgcn_global_load_lds(
        (const __attribute__((address_space(1))) void*)g,
        (__attribute__((address_space(3))) void*)l, 16, 0, 0);
}

// ---------------------------------------------------------------------------
// P0: fused prologue (round-8 verified: ~36 us saved vs 3 serial launches)
//   id <  4096: X fp32 -> bf16            (Xb)
//   id <  4864: Wqkv fp32 -> W^T bf16     (Wt,  N=3072, 48x16 tiles)
//   else      : Wout fp32 -> W^T bf16     (Wt2, N=1024, 16x16 tiles)
// ---------------------------------------------------------------------------
__global__ __launch_bounds__(256) void prep_kern(
    const float* __restrict__ x,    unsigned short* __restrict__ Xb,
    const float* __restrict__ Wqkv, unsigned short* __restrict__ Wt,
    const float* __restrict__ Wout, unsigned short* __restrict__ Wt2)
{
    __shared__ short S[64 * 65];
    const int id = blockIdx.x, tid = threadIdx.x;

    if (id < 4096) {
        int i = (id * 256 + tid) * 8;
        float4 a = *(const float4*)(x + i);
        float4 b = *(const float4*)(x + i + 4);
        int4 tv;
        short* tp = reinterpret_cast<short*>(&tv);
        tp[0] = (short)f2b(a.x); tp[1] = (short)f2b(a.y);
        tp[2] = (short)f2b(a.z); tp[3] = (short)f2b(a.w);
        tp[4] = (short)f2b(b.x); tp[5] = (short)f2b(b.y);
        tp[6] = (short)f2b(b.z); tp[7] = (short)f2b(b.w);
        *(int4*)(Xb + i) = tv;
        return;
    }

    const float* W;
    unsigned short* Wo;
    int N, n0, k0;
    if (id < 4864) {
        int t = id - 4096;                       // 768 tiles: 48 x 16
        W = Wqkv; Wo = Wt; N = 3072;
        n0 = (t % 48) * 64; k0 = (t / 48) * 64;
    } else {
        int t = id - 4864;                       // 256 tiles: 16 x 16
        W = Wout; Wo = Wt2; N = 1024;
        n0 = (t % 16) * 64; k0 = (t / 16) * 64;
    }
#pragma unroll
    for (int p = 0; p < 16; p++) {
        int idx = p * 256 + tid;
        int r = idx >> 6, c = idx & 63;          // r = k, c = n (coalesced read)
        S[c * 65 + r] = (short)f2b(W[(size_t)(k0 + r) * N + n0 + c]);
    }
    __syncthreads();
#pragma unroll
    for (int p = 0; p < 8; p++) {
        int idx = p * 256 + tid;
        int r = idx >> 5, cp = (idx & 31) * 2;   // r = n, cp = k pair
        unsigned lo = (unsigned short)S[r * 65 + cp];
        unsigned hi = (unsigned short)S[r * 65 + cp + 1];
        *(unsigned*)(Wo + (size_t)(n0 + r) * 1024 + k0 + cp) = lo | (hi << 16);
    }
}

// ---------------------------------------------------------------------------
// K1: QKV GEMM (all bf16). C[8192,3072] = Xb @ Wt^T + b
// ROUND-7 VERIFIED VERSION (80.9 us, VGPR 92, LDS 32 KB, no spills).
// 128x128 tile, BK=64, 256 threads, 2-barrier loop. 512-thread/256x128
// variants measured WORSE twice (round 4: spills; round 8: VGPR 68, 125 us).
//  * XOR-swizzled LDS (verified: conflicts 18.9M -> 786K)
//  * blob epilogue (verified round 5)
// XCD-chunked remap: 1536 blocks, 192/XCD = 8 row-tiles x 24 col-tiles.
//   Kf[bh][kt(8)][kk(2)][j(8)][lane(64)][t(8)]
//   Vf[bh][kt(8)][kk2(4)][jo(4)][lane(64)][t(8)]
// ---------------------------------------------------------------------------
__global__ __launch_bounds__(256) void qkv_gemm(
    const unsigned short* __restrict__ Xb,   // [8192][1024] bf16
    const unsigned short* __restrict__ Wt,   // [3072][1024] bf16 = W^T
    const float* __restrict__ bq,
    unsigned short* __restrict__ Qb,
    unsigned short* __restrict__ Kf,
    unsigned short* __restrict__ Vf)
{
    __shared__ __align__(16) short Sh[128 * 64 * 2];   // As | Bs ; Es = whole 32 KB
    short* As = Sh;
    short* Bs = Sh + 8192;

    // XCD-chunked remap: flat 0..1535, xcd = flat%8, 192 local = 8 rows x 24 cols
    const int flat = blockIdx.y * 24 + blockIdx.x;
    const int xcd = flat & 7, local = flat >> 3;
    const int m0 = (xcd * 8 + local / 24) * 128;
    const int n0 = (local % 24) * 128;

    const int tid = threadIdx.x;
    const int wave = tid >> 6, lane = tid & 63;
    const int quad = lane >> 4, lcol = lane & 15;
    const int wrow = (wave >> 1) * 64, wcol = (wave & 1) * 64;

    f32x4 acc[4][4];
#pragma unroll
    for (int i = 0; i < 4; i++)
#pragma unroll
        for (int j = 0; j < 4; j++) acc[i][j] = (f32x4){0.f, 0.f, 0.f, 0.f};

    const int sr = tid >> 3;                 // 0..31: row within 32-row pass
    const int g_lin = tid & 7;               // linear dest granule (8 shorts)
    const int g_src = g_lin ^ (sr & 7);      // pre-swizzled source granule
    const int swz = lcol & 7;                // read-side XOR (= row&7 of read row)

    for (int k0 = 0; k0 < 1024; k0 += 64) {
        __syncthreads();
#pragma unroll
        for (int p = 0; p < 4; p++) {
            glds16(Xb + (size_t)(m0 + p * 32 + sr) * 1024 + k0 + g_src * 8,
                   &As[(p * 32 + sr) * 64 + g_lin * 8]);
            glds16(Wt + (size_t)(n0 + p * 32 + sr) * 1024 + k0 + g_src * 8,
                   &Bs[(p * 32 + sr) * 64 + g_lin * 8]);
        }
        __syncthreads();
#pragma unroll
        for (int kk = 0; kk < 2; kk++) {
            bf16x8 a[4], b[4];
#pragma unroll
            for (int i = 0; i < 4; i++)
                a[i] = *(const bf16x8*)(&As[(wrow + 16 * i + lcol) * 64
                                            + ((kk * 4 + quad) ^ swz) * 8]);
#pragma unroll
            for (int j = 0; j < 4; j++)
                b[j] = *(const bf16x8*)(&Bs[(wcol + 16 * j + lcol) * 64
                                            + ((kk * 4 + quad) ^ swz) * 8]);
#pragma unroll
            for (int i = 0; i < 4; i++)
#pragma unroll
                for (int j = 0; j < 4; j++)
                    acc[i][j] = __builtin_amdgcn_mfma_f32_16x16x32_bf16(
                        a[i], b[j], acc[i][j], 0, 0, 0);
        }
    }
    __syncthreads();   // all ds_reads done before reusing Sh as epilogue buf

    // ---- epilogue: stage 128x128 tile into Es in blob order, copy out ----
    short* Es = Sh;                          // 32 KB = 2 blobs of 16 KB
    const int which = n0 >> 10;              // 0=Q 1=K 2=V (tile-uniform)
    const int h0 = (n0 & 1023) >> 6;         // first head in tile
    const int bb = m0 >> 10;
    const int sl0 = m0 & 1023;
    const int kt = sl0 >> 7;

#pragma unroll
    for (int j = 0; j < 4; j++) {
        int colt = wcol + 16 * j + lcol;     // 0..127
        float bias = bq[n0 + colt];
        int g = colt >> 6, e = colt & 63;
#pragma unroll
        for (int i = 0; i < 4; i++) {
#pragma unroll
            for (int reg = 0; reg < 4; reg++) {
                int ls = wrow + 16 * i + quad * 4 + reg;   // 0..127
                unsigned short v = f2b(acc[i][j][reg] + bias);
                int off;
                if (which == 0)
                    off = ls * 64 + e;
                else if (which == 1)
                    off = (e >> 5) * 4096 + (ls >> 4) * 512
                        + (((e >> 3) & 3) * 16 + (ls & 15)) * 8 + (e & 7);
                else
                    off = (ls >> 5) * 2048 + (e >> 4) * 512
                        + (((ls >> 3) & 3) * 16 + (e & 15)) * 8 + (ls & 7);
                Es[g * 8192 + off] = (short)v;
            }
        }
    }
    __syncthreads();

    // copy out 32 KB: 8 passes of 256 x b128 (two 16 KB head-blobs)
#pragma unroll
    for (int rd = 0; rd < 8; rd++) {
        int fl = rd * 2048 + tid * 8;
        int g = fl >> 13, off = fl & 8191;
        bf16x8 val = *(const bf16x8*)(&Es[fl]);
        int bh = bb * 16 + h0 + g;
        if (which == 0)
            *(bf16x8*)(Qb + ((size_t)bh * 1024 + sl0) * 64 + off) = val;
        else if (which == 1)
            *(bf16x8*)(Kf + ((size_t)bh * 8 + kt) * 8192 + off) = val;
        else
            *(bf16x8*)(Vf + ((size_t)bh * 8 + kt) * 8192 + off) = val;
    }
}

// ---------------------------------------------------------------------------
// K2: causal flash attention — EQUAL-WORK blocks + SWAPPED-OPERAND QK^T
// + T5 s_setprio around MFMA clusters (round-7 verified best).
// ---------------------------------------------------------------------------
__global__ __launch_bounds__(256, 4) void attn_kern(
    const unsigned short* __restrict__ Qb,
    const unsigned short* __restrict__ Kf,
    const unsigned short* __restrict__ Vf,
    unsigned short* __restrict__ Ob)
{
    __shared__ __align__(16) short Ps[64 * 136];    // 17.4 KB, wave-private slices

    const int xb = blockIdx.x;                      // 0..7
    const int bh = blockIdx.y;                      // 0..127
    const int pr = xb >> 1;                         // pair 0..3
    const int hf = xb & 1;                          // half-strip 0..1
    const unsigned short* Qp = Qb + (size_t)bh * 65536;
    const unsigned short* Kp = Kf + (size_t)bh * 65536;
    const unsigned short* Vp = Vf + (size_t)bh * 65536;

    const int tid = threadIdx.x;
    const int wave = tid >> 6, lane = tid & 63;
    const int quad = lane >> 4, lcol = lane & 15;
    const int hw4 = hf * 4 + wave;                  // 0..7: 16-row strip in tile
    const int qloc = hw4 * 16 + lcol;               // lane's q within its tile

    const float sc2 = 0.0450711882f;  // log2(e)/32  (scale folded into exp2)
    const int b = bh >> 4, h = bh & 15;

    for (int pass = 0; pass < 2; pass++) {
        const int qt = pass ? (7 - pr) : pr;        // q-tile index 0..7
        const int q0 = qt * 128 + hf * 64 + wave * 16;  // wave's first q row

        // Q fragments (B-operand: q=lane&15, k=quad*8+t)
        bf16x8 qa[2];
#pragma unroll
        for (int kk = 0; kk < 2; kk++)
            qa[kk] = *(const bf16x8*)(Qp + (size_t)(q0 + lcol) * 64
                                      + kk * 32 + quad * 8);

        f32x4 o_acc[4];
#pragma unroll
        for (int jo = 0; jo < 4; jo++) o_acc[jo] = (f32x4){0.f, 0.f, 0.f, 0.f};
        float l_loc = 0.f;

        for (int kt = 0; kt <= qt; kt++) {
            const bool diag = (kt == qt);
            const int jmax = diag ? hw4 : 7;        // max live 16-key tile
            const int kk2max = diag ? (hw4 >> 1) : 3;

            // S^T = K Q^T : lane holds S^T[key=16j+quad*4+reg][q=lcol]
            f32x4 scT[8];
#pragma unroll
            for (int j = 0; j < 8; j++) scT[j] = (f32x4){0.f, 0.f, 0.f, 0.f};
#pragma unroll
            for (int kk = 0; kk < 2; kk++) {
                bf16x8 kb[8];
#pragma unroll
                for (int j = 0; j < 8; j++)
                    if (j <= jmax)
                        kb[j] = *(const bf16x8*)(Kp
                            + ((size_t)((kt * 2 + kk) * 8 + j) << 9) + lane * 8);
                __builtin_amdgcn_s_setprio(1);
#pragma unroll
                for (int j = 0; j < 8; j++)
                    if (j <= jmax)
                        scT[j] = __builtin_amdgcn_mfma_f32_16x16x32_bf16(
                            kb[j], qa[kk], scT[j], 0, 0, 0);
                __builtin_amdgcn_s_setprio(0);
            }

            // max-free softmax; packed b64 store to Ps[q][key]
#pragma unroll
            for (int j = 0; j < 8; j++) {
                if (j <= jmax) {
                    float pv[4];
#pragma unroll
                    for (int r = 0; r < 4; r++) {
                        float p = exp2f(scT[j][r] * sc2);
                        if (diag && (16 * j + quad * 4 + r) > qloc) p = 0.f;
                        l_loc += p;
                        pv[r] = p;
                    }
                    ushort4 pk;
                    pk.x = f2b(pv[0]); pk.y = f2b(pv[1]);
                    pk.z = f2b(pv[2]); pk.w = f2b(pv[3]);
                    *(ushort4*)(&Ps[(wave * 16 + lcol) * 136 + 16 * j + quad * 4]) = pk;
                }
            }
            // diag with even jmax: PV's kk2max chunk reads tile jmax+1 -> zero it
            if (diag && !(jmax & 1)) {
                *(ushort4*)(&Ps[(wave * 16 + lcol) * 136 + 16 * (jmax + 1) + quad * 4]) =
                    (ushort4){0, 0, 0, 0};
            }

            // O += P @ V  (pa: A-layout b128 read of own rows; vb: 1 KB loads)
#pragma unroll
            for (int kk2 = 0; kk2 < 4; kk2++) {
                if (kk2 <= kk2max) {
                    bf16x8 pa = *(const bf16x8*)(&Ps[(wave * 16 + lcol) * 136
                                                     + kk2 * 32 + quad * 8]);
                    bf16x8 vb[4];
#pragma unroll
                    for (int jo = 0; jo < 4; jo++)
                        vb[jo] = *(const bf16x8*)(Vp
                            + ((size_t)((kt * 4 + kk2) * 4 + jo) << 9) + lane * 8);
                    __builtin_amdgcn_s_setprio(1);
#pragma unroll
                    for (int jo = 0; jo < 4; jo++)
                        o_acc[jo] = __builtin_amdgcn_mfma_f32_16x16x32_bf16(
                            pa, vb[jo], o_acc[jo], 0, 0, 0);
                    __builtin_amdgcn_s_setprio(0);
                }
            }
        }

        // l: sum the 4 quads (lanes with equal lcol hold the same q)
        l_loc += __shfl_xor(l_loc, 16);
        l_loc += __shfl_xor(l_loc, 32);
        float inv = 1.0f / l_loc;                   // inv for q = q0 + lcol
        float invq[4];
#pragma unroll
        for (int r = 0; r < 4; r++) invq[r] = __shfl(inv, quad * 4 + r);

        // write O -> [B, S, H*hd] bf16  (C-layout: row=q=quad*4+reg, col=d=16jo+lcol)
#pragma unroll
        for (int jo = 0; jo < 4; jo++) {
#pragma unroll
            for (int r = 0; r < 4; r++) {
                int q = q0 + quad * 4 + r;
                Ob[(size_t)(b * 1024 + q) * 1024 + h * 64 + 16 * jo + lcol] =
                    f2b(o_acc[jo][r] * invq[r]);
            }
        }
        l_loc = 0.f;
    }
}

// ---------------------------------------------------------------------------
// K3: out proj. P2[8192,1024](bf16) = O @ Wout + bout + X(fp32 residual)
// 128x128 tile + XOR-swizzled LDS + XCD-chunked remap (round-5 verified).
// ---------------------------------------------------------------------------
__global__ __launch_bounds__(256) void out_gemm(
    const unsigned short* __restrict__ O,
    const unsigned short* __restrict__ Wt2,  // [1024][1024] bf16 = Wout^T
    const float* __restrict__ bo,
    const float* __restrict__ X,
    unsigned short* __restrict__ P2)
{
    __shared__ __align__(16) short As[128 * 64];
    __shared__ __align__(16) short Bs[128 * 64];

    // XCD-chunked remap: 512 blocks, 64 per XCD = 8 row-tiles x 8 col-tiles
    const int flat = blockIdx.y * 8 + blockIdx.x;
    const int xcd = flat & 7, local = flat >> 3;
    const int m0 = (xcd * 8 + (local >> 3)) * 128;
    const int n0 = (local & 7) * 128;

    const int tid = threadIdx.x;
    const int wave = tid >> 6, lane = tid & 63;
    const int quad = lane >> 4, lcol = lane & 15;
    const int wrow = (wave >> 1) * 64, wcol = (wave & 1) * 64;

    f32x4 acc[4][4];
#pragma unroll
    for (int i = 0; i < 4; i++)
#pragma unroll
        for (int j = 0; j < 4; j++) acc[i][j] = (f32x4){0.f, 0.f, 0.f, 0.f};

    const int sr = tid >> 3;                 // 0..31
    const int g_lin = tid & 7;
    const int g_src = g_lin ^ (sr & 7);
    const int swz = lcol & 7;

    for (int k0 = 0; k0 < 1024; k0 += 64) {
        __syncthreads();
#pragma unroll
        for (int p = 0; p < 4; p++) {
            glds16(O + (size_t)(m0 + p * 32 + sr) * 1024 + k0 + g_src * 8,
                   &As[(p * 32 + sr) * 64 + g_lin * 8]);
            glds16(Wt2 + (size_t)(n0 + p * 32 + sr) * 1024 + k0 + g_src * 8,
                   &Bs[(p * 32 + sr) * 64 + g_lin * 8]);
        }
        __syncthreads();
#pragma unroll
        for (int kk = 0; kk < 2; kk++) {
            bf16x8 a[4], b[4];
#pragma unroll
            for (int i = 0; i < 4; i++)
                a[i] = *(const bf16x8*)(&As[(wrow + 16 * i + lcol) * 64
                                            + ((kk * 4 + quad) ^ swz) * 8]);
#pragma unroll
            for (int j = 0; j < 4; j++)
                b[j] = *(const bf16x8*)(&Bs[(wcol + 16 * j + lcol) * 64
                                            + ((kk * 4 + quad) ^ swz) * 8]);
#pragma unroll
            for (int i = 0; i < 4; i++)
#pragma unroll
                for (int j = 0; j < 4; j++)
                    acc[i][j] = __builtin_amdgcn_mfma_f32_16x16x32_bf16(
                        a[i], b[j], acc[i][j], 0, 0, 0);
        }
    }

#pragma unroll
    for (int j = 0; j < 4; j++) {
        int c = n0 + wcol + 16 * j + lcol;
        float bias = bo[c];
#pragma unroll
        for (int i = 0; i < 4; i++) {
#pragma unroll
            for (int reg = 0; reg < 4; reg++) {
                int r = m0 + wrow + 16 * i + quad * 4 + reg;
                float v = acc[i][j][reg] + bias + X[(size_t)r * 1024 + c];
                P2[(size_t)r * 1024 + c] = f2b(v);
            }
        }
    }
}

// ---------------------------------------------------------------------------
// K4: LayerNorm over last dim (1024), bf16 in / fp32 out, one block per row
// ---------------------------------------------------------------------------
__global__ __launch_bounds__(256) void ln_kern(
    const unsigned short* __restrict__ P2,
    const float* __restrict__ G,
    const float* __restrict__ Bt,
    float* __restrict__ out)
{
    const int row = blockIdx.x, tid = threadIdx.x;
    const size_t base = (size_t)row * 1024 + tid * 4;

    int2 raw = *(const int2*)(P2 + base);
    float v[4];
    v[0] = b2f((unsigned short)(raw.x & 0xffff));
    v[1] = b2f((unsigned short)((unsigned)raw.x >> 16));
    v[2] = b2f((unsigned short)(raw.y & 0xffff));
    v[3] = b2f((unsigned short)((unsigned)raw.y >> 16));

    float sum = v[0] + v[1] + v[2] + v[3];
    float sq = v[0] * v[0] + v[1] * v[1] + v[2] * v[2] + v[3] * v[3];
#pragma unroll
    for (int m = 1; m < 64; m <<= 1) {
        sum += __shfl_xor(sum, m);
        sq += __shfl_xor(sq, m);
    }
    __shared__ float rs[4], rq[4];
    const int wave = tid >> 6, lane = tid & 63;
    if (lane == 0) { rs[wave] = sum; rq[wave] = sq; }
    __syncthreads();
    sum = rs[0] + rs[1] + rs[2] + rs[3];
    sq = rq[0] + rq[1] + rq[2] + rq[3];

    float mean = sum * (1.0f / 1024.0f);
    float var = fmaxf(sq * (1.0f / 1024.0f) - mean * mean, 0.0f);
    float rstd = rsqrtf(var + 1e-5f);

    float4 g = *(const float4*)(G + tid * 4);
    float4 be = *(const float4*)(Bt + tid * 4);

    float4 o;
    o.x = (v[0] - mean) * rstd * g.x + be.x;
    o.y = (v[1] - mean) * rstd * g.y + be.y;
    o.z = (v[2] - mean) * rstd * g.z + be.z;
    o.w = (v[3] - mean) * rstd * g.w + be.w;
    *(float4*)(out + base) = o;
}

// ---------------------------------------------------------------------------
// Buffer plan:
//   d_out (32 MB): Qb bf16 @0, Ob bf16 @16M; final fp32 result overwrites.
//   d_ws  (56 MB): Kf @0, Vf @16M, Wt2 @32M (2M), Xb @34M (16M), Wt @50M (6M)
//   P2 bf16 @34M aliases Xb (dead after qkv_gemm).
// ---------------------------------------------------------------------------
extern "C" void kernel_launch(void* const* d_in, const int* in_sizes, int n_in,
                              void* d_out, int out_size, void* d_ws, size_t ws_size,
                              hipStream_t stream) {
    const float* x    = (const float*)d_in[0];
    const float* Wqkv = (const float*)d_in[1];
    const float* bqkv = (const float*)d_in[2];
    const float* Wout = (const float*)d_in[3];
    const float* bout = (const float*)d_in[4];
    const float* gam  = (const float*)d_in[5];
    const float* bet  = (const float*)d_in[6];
    float* out = (float*)d_out;

    char* ws = (char*)d_ws;
    const size_t MB = (size_t)1024 * 1024;

    unsigned short* Qb  = (unsigned short*)d_out;
    unsigned short* Ob  = (unsigned short*)d_out + 8388608;
    unsigned short* Kf  = (unsigned short*)(ws);
    unsigned short* Vf  = (unsigned short*)(ws + 16 * MB);
    unsigned short* Wt2 = (unsigned short*)(ws + 32 * MB);
    unsigned short* Xb  = (unsigned short*)(ws + 34 * MB);
    unsigned short* Wt  = (unsigned short*)(ws + 50 * MB);
    unsigned short* P2  = (unsigned short*)(ws + 34 * MB);   // alias Xb

    prep_kern<<<5120, 256, 0, stream>>>(x, Xb, Wqkv, Wt, Wout, Wt2);
    qkv_gemm<<<dim3(24, 64), 256, 0, stream>>>(Xb, Wt, bqkv, Qb, Kf, Vf);
    attn_kern<<<dim3(8, 128), 256, 0, stream>>>(Qb, Kf, Vf, Ob);
    out_gemm<<<dim3(8, 64), 256, 0, stream>>>(Ob, Wt2, bout, x, P2);
    ln_kern<<<8192, 256, 0, stream>>>(P2, gam, bet, out);
}

// Round 11
// 261.504 us; speedup vs baseline: 1.0673x; 1.0125x over previous
//
#include <hip/hip_runtime.h>
#include <math.h>

typedef __attribute__((ext_vector_type(8))) short bf16x8;
typedef __attribute__((ext_vector_type(4))) float f32x4;

#define DEV __device__ __forceinline__

DEV unsigned short f2b(float f) {
    union { float f; unsigned u; } x;
    x.f = f;
    unsigned r = x.u + 0x7fff + ((x.u >> 16) & 1);  // RNE
    return (unsigned short)(r >> 16);
}
DEV float b2f(unsigned short u) {
    union { unsigned u; float f; } x;
    x.u = ((unsigned)u) << 16;
    return x.f;
}

// async global->LDS, 16B per lane; LDS dest must be wave-uniform base + lane*16
DEV void glds16(const void* g, void* l) {
    __builtin_amdgcn_global_load_lds(
        (const __attribute__((address_space(1))) void*)g,
        (__attribute__((address_space(3))) void*)l, 16, 0, 0);
}

// ---------------------------------------------------------------------------
// P0: fused prologue (round-8 verified)
//   id <  4096: X fp32 -> bf16            (Xb)
//   id <  4864: Wqkv fp32 -> W^T bf16     (Wt,  N=3072, 48x16 tiles)
//   else      : Wout fp32 -> W^T bf16     (Wt2, N=1024, 16x16 tiles)
// ---------------------------------------------------------------------------
__global__ __launch_bounds__(256) void prep_kern(
    const float* __restrict__ x,    unsigned short* __restrict__ Xb,
    const float* __restrict__ Wqkv, unsigned short* __restrict__ Wt,
    const float* __restrict__ Wout, unsigned short* __restrict__ Wt2)
{
    __shared__ short S[64 * 65];
    const int id = blockIdx.x, tid = threadIdx.x;

    if (id < 4096) {
        int i = (id * 256 + tid) * 8;
        float4 a = *(const float4*)(x + i);
        float4 b = *(const float4*)(x + i + 4);
        int4 tv;
        short* tp = reinterpret_cast<short*>(&tv);
        tp[0] = (short)f2b(a.x); tp[1] = (short)f2b(a.y);
        tp[2] = (short)f2b(a.z); tp[3] = (short)f2b(a.w);
        tp[4] = (short)f2b(b.x); tp[5] = (short)f2b(b.y);
        tp[6] = (short)f2b(b.z); tp[7] = (short)f2b(b.w);
        *(int4*)(Xb + i) = tv;
        return;
    }

    const float* W;
    unsigned short* Wo;
    int N, n0, k0;
    if (id < 4864) {
        int t = id - 4096;                       // 768 tiles: 48 x 16
        W = Wqkv; Wo = Wt; N = 3072;
        n0 = (t % 48) * 64; k0 = (t / 48) * 64;
    } else {
        int t = id - 4864;                       // 256 tiles: 16 x 16
        W = Wout; Wo = Wt2; N = 1024;
        n0 = (t % 16) * 64; k0 = (t / 16) * 64;
    }
#pragma unroll
    for (int p = 0; p < 16; p++) {
        int idx = p * 256 + tid;
        int r = idx >> 6, c = idx & 63;          // r = k, c = n (coalesced read)
        S[c * 65 + r] = (short)f2b(W[(size_t)(k0 + r) * N + n0 + c]);
    }
    __syncthreads();
#pragma unroll
    for (int p = 0; p < 8; p++) {
        int idx = p * 256 + tid;
        int r = idx >> 5, cp = (idx & 31) * 2;   // r = n, cp = k pair
        unsigned lo = (unsigned short)S[r * 65 + cp];
        unsigned hi = (unsigned short)S[r * 65 + cp + 1];
        *(unsigned*)(Wo + (size_t)(n0 + r) * 1024 + k0 + cp) = lo | (hi << 16);
    }
}

// ---------------------------------------------------------------------------
// K1: QKV GEMM (all bf16). C[8192,3072] = Xb @ Wt^T + b
// ROUND-7/9 VERIFIED VERSION — exact mapping that passed twice (row-major
// local -> (m,n)). Round-10's col-major variant is implicated in a replay
// divergence and is reverted.
//  * XOR-swizzled LDS (verified: conflicts 18.9M -> 786K)
//  * blob epilogue (verified round 5)
//   Kf[bh][kt(8)][kk(2)][j(8)][lane(64)][t(8)]
//   Vf[bh][kt(8)][kk2(4)][jo(4)][lane(64)][t(8)]
// ---------------------------------------------------------------------------
__global__ __launch_bounds__(256) void qkv_gemm(
    const unsigned short* __restrict__ Xb,   // [8192][1024] bf16
    const unsigned short* __restrict__ Wt,   // [3072][1024] bf16 = W^T
    const float* __restrict__ bq,
    unsigned short* __restrict__ Qb,
    unsigned short* __restrict__ Kf,
    unsigned short* __restrict__ Vf)
{
    __shared__ __align__(16) short Sh[128 * 64 * 2];   // As | Bs ; Es = whole 32 KB
    short* As = Sh;
    short* Bs = Sh + 8192;

    // XCD-chunked remap: flat 0..1535, xcd = flat%8, 192 local = 8 rows x 24 cols
    const int flat = blockIdx.y * 24 + blockIdx.x;
    const int xcd = flat & 7, local = flat >> 3;
    const int m0 = (xcd * 8 + local / 24) * 128;
    const int n0 = (local % 24) * 128;

    const int tid = threadIdx.x;
    const int wave = tid >> 6, lane = tid & 63;
    const int quad = lane >> 4, lcol = lane & 15;
    const int wrow = (wave >> 1) * 64, wcol = (wave & 1) * 64;

    f32x4 acc[4][4];
#pragma unroll
    for (int i = 0; i < 4; i++)
#pragma unroll
        for (int j = 0; j < 4; j++) acc[i][j] = (f32x4){0.f, 0.f, 0.f, 0.f};

    const int sr = tid >> 3;                 // 0..31: row within 32-row pass
    const int g_lin = tid & 7;               // linear dest granule (8 shorts)
    const int g_src = g_lin ^ (sr & 7);      // pre-swizzled source granule
    const int swz = lcol & 7;                // read-side XOR (= row&7 of read row)

    for (int k0 = 0; k0 < 1024; k0 += 64) {
        __syncthreads();
#pragma unroll
        for (int p = 0; p < 4; p++) {
            glds16(Xb + (size_t)(m0 + p * 32 + sr) * 1024 + k0 + g_src * 8,
                   &As[(p * 32 + sr) * 64 + g_lin * 8]);
            glds16(Wt + (size_t)(n0 + p * 32 + sr) * 1024 + k0 + g_src * 8,
                   &Bs[(p * 32 + sr) * 64 + g_lin * 8]);
        }
        __syncthreads();
#pragma unroll
        for (int kk = 0; kk < 2; kk++) {
            bf16x8 a[4], b[4];
#pragma unroll
            for (int i = 0; i < 4; i++)
                a[i] = *(const bf16x8*)(&As[(wrow + 16 * i + lcol) * 64
                                            + ((kk * 4 + quad) ^ swz) * 8]);
#pragma unroll
            for (int j = 0; j < 4; j++)
                b[j] = *(const bf16x8*)(&Bs[(wcol + 16 * j + lcol) * 64
                                            + ((kk * 4 + quad) ^ swz) * 8]);
#pragma unroll
            for (int i = 0; i < 4; i++)
#pragma unroll
                for (int j = 0; j < 4; j++)
                    acc[i][j] = __builtin_amdgcn_mfma_f32_16x16x32_bf16(
                        a[i], b[j], acc[i][j], 0, 0, 0);
        }
    }
    __syncthreads();   // all ds_reads done before reusing Sh as epilogue buf

    // ---- epilogue: stage 128x128 tile into Es in blob order, copy out ----
    short* Es = Sh;                          // 32 KB = 2 blobs of 16 KB
    const int which = n0 >> 10;              // 0=Q 1=K 2=V (tile-uniform)
    const int h0 = (n0 & 1023) >> 6;         // first head in tile
    const int bb = m0 >> 10;
    const int sl0 = m0 & 1023;
    const int kt = sl0 >> 7;

#pragma unroll
    for (int j = 0; j < 4; j++) {
        int colt = wcol + 16 * j + lcol;     // 0..127
        float bias = bq[n0 + colt];
        int g = colt >> 6, e = colt & 63;
#pragma unroll
        for (int i = 0; i < 4; i++) {
#pragma unroll
            for (int reg = 0; reg < 4; reg++) {
                int ls = wrow + 16 * i + quad * 4 + reg;   // 0..127
                unsigned short v = f2b(acc[i][j][reg] + bias);
                int off;
                if (which == 0)
                    off = ls * 64 + e;
                else if (which == 1)
                    off = (e >> 5) * 4096 + (ls >> 4) * 512
                        + (((e >> 3) & 3) * 16 + (ls & 15)) * 8 + (e & 7);
                else
                    off = (ls >> 5) * 2048 + (e >> 4) * 512
                        + (((ls >> 3) & 3) * 16 + (e & 15)) * 8 + (ls & 7);
                Es[g * 8192 + off] = (short)v;
            }
        }
    }
    __syncthreads();

    // copy out 32 KB: 8 passes of 256 x b128 (two 16 KB head-blobs)
#pragma unroll
    for (int rd = 0; rd < 8; rd++) {
        int fl = rd * 2048 + tid * 8;
        int g = fl >> 13, off = fl & 8191;
        bf16x8 val = *(const bf16x8*)(&Es[fl]);
        int bh = bb * 16 + h0 + g;
        if (which == 0)
            *(bf16x8*)(Qb + ((size_t)bh * 1024 + sl0) * 64 + off) = val;
        else if (which == 1)
            *(bf16x8*)(Kf + ((size_t)bh * 8 + kt) * 8192 + off) = val;
        else
            *(bf16x8*)(Vf + ((size_t)bh * 8 + kt) * 8192 + off) = val;
    }
}

// ---------------------------------------------------------------------------
// K2: causal flash attention — EQUAL-WORK blocks + SWAPPED-OPERAND QK^T
// + s_setprio (round-7 verified). Grid (128, 8): XCD = bh%8 -> each XCD
// owns 16 heads, K/V footprint 16x256KB = 4 MB = one L2 (K/V loads L2-hit).
// ---------------------------------------------------------------------------
__global__ __launch_bounds__(256, 4) void attn_kern(
    const unsigned short* __restrict__ Qb,
    const unsigned short* __restrict__ Kf,
    const unsigned short* __restrict__ Vf,
    unsigned short* __restrict__ Ob)
{
    __shared__ __align__(16) short Ps[64 * 136];    // 17.4 KB, wave-private slices

    const int bh = blockIdx.x;                      // 0..127  (XCD = bh%8)
    const int xb = blockIdx.y;                      // 0..7
    const int pr = xb >> 1;                         // pair 0..3
    const int hf = xb & 1;                          // half-strip 0..1
    const unsigned short* Qp = Qb + (size_t)bh * 65536;
    const unsigned short* Kp = Kf + (size_t)bh * 65536;
    const unsigned short* Vp = Vf + (size_t)bh * 65536;

    const int tid = threadIdx.x;
    const int wave = tid >> 6, lane = tid & 63;
    const int quad = lane >> 4, lcol = lane & 15;
    const int hw4 = hf * 4 + wave;                  // 0..7: 16-row strip in tile
    const int qloc = hw4 * 16 + lcol;               // lane's q within its tile

    const float sc2 = 0.0450711882f;  // log2(e)/32  (scale folded into exp2)
    const int b = bh >> 4, h = bh & 15;

    for (int pass = 0; pass < 2; pass++) {
        const int qt = pass ? (7 - pr) : pr;        // q-tile index 0..7
        const int q0 = qt * 128 + hf * 64 + wave * 16;  // wave's first q row

        // Q fragments (B-operand: q=lane&15, k=quad*8+t)
        bf16x8 qa[2];
#pragma unroll
        for (int kk = 0; kk < 2; kk++)
            qa[kk] = *(const bf16x8*)(Qp + (size_t)(q0 + lcol) * 64
                                      + kk * 32 + quad * 8);

        f32x4 o_acc[4];
#pragma unroll
        for (int jo = 0; jo < 4; jo++) o_acc[jo] = (f32x4){0.f, 0.f, 0.f, 0.f};
        float l_loc = 0.f;

        for (int kt = 0; kt <= qt; kt++) {
            const bool diag = (kt == qt);
            const int jmax = diag ? hw4 : 7;        // max live 16-key tile
            const int kk2max = diag ? (hw4 >> 1) : 3;

            // S^T = K Q^T : lane holds S^T[key=16j+quad*4+reg][q=lcol]
            f32x4 scT[8];
#pragma unroll
            for (int j = 0; j < 8; j++) scT[j] = (f32x4){0.f, 0.f, 0.f, 0.f};
#pragma unroll
            for (int kk = 0; kk < 2; kk++) {
                bf16x8 kb[8];
#pragma unroll
                for (int j = 0; j < 8; j++)
                    if (j <= jmax)
                        kb[j] = *(const bf16x8*)(Kp
                            + ((size_t)((kt * 2 + kk) * 8 + j) << 9) + lane * 8);
                __builtin_amdgcn_s_setprio(1);
#pragma unroll
                for (int j = 0; j < 8; j++)
                    if (j <= jmax)
                        scT[j] = __builtin_amdgcn_mfma_f32_16x16x32_bf16(
                            kb[j], qa[kk], scT[j], 0, 0, 0);
                __builtin_amdgcn_s_setprio(0);
            }

            // max-free softmax; packed b64 store to Ps[q][key]
#pragma unroll
            for (int j = 0; j < 8; j++) {
                if (j <= jmax) {
                    float pv[4];
#pragma unroll
                    for (int r = 0; r < 4; r++) {
                        float p = exp2f(scT[j][r] * sc2);
                        if (diag && (16 * j + quad * 4 + r) > qloc) p = 0.f;
                        l_loc += p;
                        pv[r] = p;
                    }
                    ushort4 pk;
                    pk.x = f2b(pv[0]); pk.y = f2b(pv[1]);
                    pk.z = f2b(pv[2]); pk.w = f2b(pv[3]);
                    *(ushort4*)(&Ps[(wave * 16 + lcol) * 136 + 16 * j + quad * 4]) = pk;
                }
            }
            // diag with even jmax: PV's kk2max chunk reads tile jmax+1 -> zero it
            if (diag && !(jmax & 1)) {
                *(ushort4*)(&Ps[(wave * 16 + lcol) * 136 + 16 * (jmax + 1) + quad * 4]) =
                    (ushort4){0, 0, 0, 0};
            }

            // O += P @ V  (pa: A-layout b128 read of own rows; vb: 1 KB loads)
#pragma unroll
            for (int kk2 = 0; kk2 < 4; kk2++) {
                if (kk2 <= kk2max) {
                    bf16x8 pa = *(const bf16x8*)(&Ps[(wave * 16 + lcol) * 136
                                                     + kk2 * 32 + quad * 8]);
                    bf16x8 vb[4];
#pragma unroll
                    for (int jo = 0; jo < 4; jo++)
                        vb[jo] = *(const bf16x8*)(Vp
                            + ((size_t)((kt * 4 + kk2) * 4 + jo) << 9) + lane * 8);
                    __builtin_amdgcn_s_setprio(1);
#pragma unroll
                    for (int jo = 0; jo < 4; jo++)
                        o_acc[jo] = __builtin_amdgcn_mfma_f32_16x16x32_bf16(
                            pa, vb[jo], o_acc[jo], 0, 0, 0);
                    __builtin_amdgcn_s_setprio(0);
                }
            }
        }

        // l: sum the 4 quads (lanes with equal lcol hold the same q)
        l_loc += __shfl_xor(l_loc, 16);
        l_loc += __shfl_xor(l_loc, 32);
        float inv = 1.0f / l_loc;                   // inv for q = q0 + lcol
        float invq[4];
#pragma unroll
        for (int r = 0; r < 4; r++) invq[r] = __shfl(inv, quad * 4 + r);

        // write O -> [B, S, H*hd] bf16  (C-layout: row=q=quad*4+reg, col=d=16jo+lcol)
#pragma unroll
        for (int jo = 0; jo < 4; jo++) {
#pragma unroll
            for (int r = 0; r < 4; r++) {
                int q = q0 + quad * 4 + r;
                Ob[(size_t)(b * 1024 + q) * 1024 + h * 64 + 16 * jo + lcol] =
                    f2b(o_acc[jo][r] * invq[r]);
            }
        }
        l_loc = 0.f;
    }
}

// ---------------------------------------------------------------------------
// K3: out proj. P2[8192,1024](bf16) = O @ Wout + bout + X(fp32 residual)
// 128x128 tile + XOR-swizzled LDS + XCD-chunked remap (round-5 verified).
// ---------------------------------------------------------------------------
__global__ __launch_bounds__(256) void out_gemm(
    const unsigned short* __restrict__ O,
    const unsigned short* __restrict__ Wt2,  // [1024][1024] bf16 = Wout^T
    const float* __restrict__ bo,
    const float* __restrict__ X,
    unsigned short* __restrict__ P2)
{
    __shared__ __align__(16) short As[128 * 64];
    __shared__ __align__(16) short Bs[128 * 64];

    // XCD-chunked remap: 512 blocks, 64 per XCD = 8 row-tiles x 8 col-tiles
    const int flat = blockIdx.y * 8 + blockIdx.x;
    const int xcd = flat & 7, local = flat >> 3;
    const int m0 = (xcd * 8 + (local >> 3)) * 128;
    const int n0 = (local & 7) * 128;

    const int tid = threadIdx.x;
    const int wave = tid >> 6, lane = tid & 63;
    const int quad = lane >> 4, lcol = lane & 15;
    const int wrow = (wave >> 1) * 64, wcol = (wave & 1) * 64;

    f32x4 acc[4][4];
#pragma unroll
    for (int i = 0; i < 4; i++)
#pragma unroll
        for (int j = 0; j < 4; j++) acc[i][j] = (f32x4){0.f, 0.f, 0.f, 0.f};

    const int sr = tid >> 3;                 // 0..31
    const int g_lin = tid & 7;
    const int g_src = g_lin ^ (sr & 7);
    const int swz = lcol & 7;

    for (int k0 = 0; k0 < 1024; k0 += 64) {
        __syncthreads();
#pragma unroll
        for (int p = 0; p < 4; p++) {
            glds16(O + (size_t)(m0 + p * 32 + sr) * 1024 + k0 + g_src * 8,
                   &As[(p * 32 + sr) * 64 + g_lin * 8]);
            glds16(Wt2 + (size_t)(n0 + p * 32 + sr) * 1024 + k0 + g_src * 8,
                   &Bs[(p * 32 + sr) * 64 + g_lin * 8]);
        }
        __syncthreads();
#pragma unroll
        for (int kk = 0; kk < 2; kk++) {
            bf16x8 a[4], b[4];
#pragma unroll
            for (int i = 0; i < 4; i++)
                a[i] = *(const bf16x8*)(&As[(wrow + 16 * i + lcol) * 64
                                            + ((kk * 4 + quad) ^ swz) * 8]);
#pragma unroll
            for (int j = 0; j < 4; j++)
                b[j] = *(const bf16x8*)(&Bs[(wcol + 16 * j + lcol) * 64
                                            + ((kk * 4 + quad) ^ swz) * 8]);
#pragma unroll
            for (int i = 0; i < 4; i++)
#pragma unroll
                for (int j = 0; j < 4; j++)
                    acc[i][j] = __builtin_amdgcn_mfma_f32_16x16x32_bf16(
                        a[i], b[j], acc[i][j], 0, 0, 0);
        }
    }

#pragma unroll
    for (int j = 0; j < 4; j++) {
        int c = n0 + wcol + 16 * j + lcol;
        float bias = bo[c];
#pragma unroll
        for (int i = 0; i < 4; i++) {
#pragma unroll
            for (int reg = 0; reg < 4; reg++) {
                int r = m0 + wrow + 16 * i + quad * 4 + reg;
                float v = acc[i][j][reg] + bias + X[(size_t)r * 1024 + c];
                P2[(size_t)r * 1024 + c] = f2b(v);
            }
        }
    }
}

// ---------------------------------------------------------------------------
// K4: LayerNorm over last dim (1024), bf16 in / fp32 out, one block per row
// ---------------------------------------------------------------------------
__global__ __launch_bounds__(256) void ln_kern(
    const unsigned short* __restrict__ P2,
    const float* __restrict__ G,
    const float* __restrict__ Bt,
    float* __restrict__ out)
{
    const int row = blockIdx.x, tid = threadIdx.x;
    const size_t base = (size_t)row * 1024 + tid * 4;

    int2 raw = *(const int2*)(P2 + base);
    float v[4];
    v[0] = b2f((unsigned short)(raw.x & 0xffff));
    v[1] = b2f((unsigned short)((unsigned)raw.x >> 16));
    v[2] = b2f((unsigned short)(raw.y & 0xffff));
    v[3] = b2f((unsigned short)((unsigned)raw.y >> 16));

    float sum = v[0] + v[1] + v[2] + v[3];
    float sq = v[0] * v[0] + v[1] * v[1] + v[2] * v[2] + v[3] * v[3];
#pragma unroll
    for (int m = 1; m < 64; m <<= 1) {
        sum += __shfl_xor(sum, m);
        sq += __shfl_xor(sq, m);
    }
    __shared__ float rs[4], rq[4];
    const int wave = tid >> 6, lane = tid & 63;
    if (lane == 0) { rs[wave] = sum; rq[wave] = sq; }
    __syncthreads();
    sum = rs[0] + rs[1] + rs[2] + rs[3];
    sq = rq[0] + rq[1] + rq[2] + rq[3];

    float mean = sum * (1.0f / 1024.0f);
    float var = fmaxf(sq * (1.0f / 1024.0f) - mean * mean, 0.0f);
    float rstd = rsqrtf(var + 1e-5f);

    float4 g = *(const float4*)(G + tid * 4);
    float4 be = *(const float4*)(Bt + tid * 4);

    float4 o;
    o.x = (v[0] - mean) * rstd * g.x + be.x;
    o.y = (v[1] - mean) * rstd * g.y + be.y;
    o.z = (v[2] - mean) * rstd * g.z + be.z;
    o.w = (v[3] - mean) * rstd * g.w + be.w;
    *(float4*)(out + base) = o;
}

// ---------------------------------------------------------------------------
// Buffer plan:
//   d_out (32 MB): Qb bf16 @0, Ob bf16 @16M; final fp32 result overwrites.
//   d_ws  (56 MB): Kf @0, Vf @16M, Wt2 @32M (2M), Xb @34M (16M), Wt @50M (6M)
//   P2 bf16 @34M aliases Xb (dead after qkv_gemm).
// ---------------------------------------------------------------------------
extern "C" void kernel_launch(void* const* d_in, const int* in_sizes, int n_in,
                              void* d_out, int out_size, void* d_ws, size_t ws_size,
                              hipStream_t stream) {
    const float* x    = (const float*)d_in[0];
    const float* Wqkv = (const float*)d_in[1];
    const float* bqkv = (const float*)d_in[2];
    const float* Wout = (const float*)d_in[3];
    const float* bout = (const float*)d_in[4];
    const float* gam  = (const float*)d_in[5];
    const float* bet  = (const float*)d_in[6];
    float* out = (float*)d_out;

    char* ws = (char*)d_ws;
    const size_t MB = (size_t)1024 * 1024;

    unsigned short* Qb  = (unsigned short*)d_out;
    unsigned short* Ob  = (unsigned short*)d_out + 8388608;
    unsigned short* Kf  = (unsigned short*)(ws);
    unsigned short* Vf  = (unsigned short*)(ws + 16 * MB);
    unsigned short* Wt2 = (unsigned short*)(ws + 32 * MB);
    unsigned short* Xb  = (unsigned short*)(ws + 34 * MB);
    unsigned short* Wt  = (unsigned short*)(ws + 50 * MB);
    unsigned short* P2  = (unsigned short*)(ws + 34 * MB);   // alias Xb

    prep_kern<<<5120, 256, 0, stream>>>(x, Xb, Wqkv, Wt, Wout, Wt2);
    qkv_gemm<<<dim3(24, 64), 256, 0, stream>>>(Xb, Wt, bqkv, Qb, Kf, Vf);
    attn_kern<<<dim3(128, 8), 256, 0, stream>>>(Qb, Kf, Vf, Ob);
    out_gemm<<<dim3(8, 64), 256, 0, stream>>>(Ob, Wt2, bout, x, P2);
    ln_kern<<<8192, 256, 0, stream>>>(P2, gam, bet, out);
}

// Round 12
// 253.585 us; speedup vs baseline: 1.1007x; 1.0312x over previous
//
#include <hip/hip_runtime.h>
#include <math.h>

typedef __attribute__((ext_vector_type(8))) short bf16x8;
typedef __attribute__((ext_vector_type(4))) float f32x4;

#define DEV __device__ __forceinline__

DEV unsigned short f2b(float f) {
    union { float f; unsigned u; } x;
    x.f = f;
    unsigned r = x.u + 0x7fff + ((x.u >> 16) & 1);  // RNE
    return (unsigned short)(r >> 16);
}
DEV float b2f(unsigned short u) {
    union { unsigned u; float f; } x;
    x.u = ((unsigned)u) << 16;
    return x.f;
}

// async global->LDS, 16B per lane; LDS dest must be wave-uniform base + lane*16
DEV void glds16(const void* g, void* l) {
    __builtin_amdgcn_global_load_lds(
        (const __attribute__((address_space(1))) void*)g,
        (__attribute__((address_space(3))) void*)l, 16, 0, 0);
}

// ---------------------------------------------------------------------------
// P0: fused prologue (round-8 verified)
//   id <  4096: X fp32 -> bf16            (Xb)
//   id <  4864: Wqkv fp32 -> W^T bf16     (Wt,  N=3072, 48x16 tiles)
//   else      : Wout fp32 -> W^T bf16     (Wt2, N=1024, 16x16 tiles)
// ---------------------------------------------------------------------------
__global__ __launch_bounds__(256) void prep_kern(
    const float* __restrict__ x,    unsigned short* __restrict__ Xb,
    const float* __restrict__ Wqkv, unsigned short* __restrict__ Wt,
    const float* __restrict__ Wout, unsigned short* __restrict__ Wt2)
{
    __shared__ short S[64 * 65];
    const int id = blockIdx.x, tid = threadIdx.x;

    if (id < 4096) {
        int i = (id * 256 + tid) * 8;
        float4 a = *(const float4*)(x + i);
        float4 b = *(const float4*)(x + i + 4);
        int4 tv;
        short* tp = reinterpret_cast<short*>(&tv);
        tp[0] = (short)f2b(a.x); tp[1] = (short)f2b(a.y);
        tp[2] = (short)f2b(a.z); tp[3] = (short)f2b(a.w);
        tp[4] = (short)f2b(b.x); tp[5] = (short)f2b(b.y);
        tp[6] = (short)f2b(b.z); tp[7] = (short)f2b(b.w);
        *(int4*)(Xb + i) = tv;
        return;
    }

    const float* W;
    unsigned short* Wo;
    int N, n0, k0;
    if (id < 4864) {
        int t = id - 4096;                       // 768 tiles: 48 x 16
        W = Wqkv; Wo = Wt; N = 3072;
        n0 = (t % 48) * 64; k0 = (t / 48) * 64;
    } else {
        int t = id - 4864;                       // 256 tiles: 16 x 16
        W = Wout; Wo = Wt2; N = 1024;
        n0 = (t % 16) * 64; k0 = (t / 16) * 64;
    }
#pragma unroll
    for (int p = 0; p < 16; p++) {
        int idx = p * 256 + tid;
        int r = idx >> 6, c = idx & 63;          // r = k, c = n (coalesced read)
        S[c * 65 + r] = (short)f2b(W[(size_t)(k0 + r) * N + n0 + c]);
    }
    __syncthreads();
#pragma unroll
    for (int p = 0; p < 8; p++) {
        int idx = p * 256 + tid;
        int r = idx >> 5, cp = (idx & 31) * 2;   // r = n, cp = k pair
        unsigned lo = (unsigned short)S[r * 65 + cp];
        unsigned hi = (unsigned short)S[r * 65 + cp + 1];
        *(unsigned*)(Wo + (size_t)(n0 + r) * 1024 + k0 + cp) = lo | (hi << 16);
    }
}

// ---------------------------------------------------------------------------
// K1: QKV GEMM (all bf16). C[8192,3072] = Xb @ Wt^T + b
// ROUND-7/9/11 VERIFIED VERSION (passed 3x). 128x128 tile, 256 threads,
// 2-barrier loop, XOR-swizzled LDS, blob epilogue, row-major XCD remap.
//   Kf[bh][kt(8)][kk(2)][j(8)][lane(64)][t(8)]
//   Vf[bh][kt(8)][kk2(4)][jo(4)][lane(64)][t(8)]
// ---------------------------------------------------------------------------
__global__ __launch_bounds__(256) void qkv_gemm(
    const unsigned short* __restrict__ Xb,   // [8192][1024] bf16
    const unsigned short* __restrict__ Wt,   // [3072][1024] bf16 = W^T
    const float* __restrict__ bq,
    unsigned short* __restrict__ Qb,
    unsigned short* __restrict__ Kf,
    unsigned short* __restrict__ Vf)
{
    __shared__ __align__(16) short Sh[128 * 64 * 2];   // As | Bs ; Es = whole 32 KB
    short* As = Sh;
    short* Bs = Sh + 8192;

    // XCD-chunked remap: flat 0..1535, xcd = flat%8, 192 local = 8 rows x 24 cols
    const int flat = blockIdx.y * 24 + blockIdx.x;
    const int xcd = flat & 7, local = flat >> 3;
    const int m0 = (xcd * 8 + local / 24) * 128;
    const int n0 = (local % 24) * 128;

    const int tid = threadIdx.x;
    const int wave = tid >> 6, lane = tid & 63;
    const int quad = lane >> 4, lcol = lane & 15;
    const int wrow = (wave >> 1) * 64, wcol = (wave & 1) * 64;

    f32x4 acc[4][4];
#pragma unroll
    for (int i = 0; i < 4; i++)
#pragma unroll
        for (int j = 0; j < 4; j++) acc[i][j] = (f32x4){0.f, 0.f, 0.f, 0.f};

    const int sr = tid >> 3;                 // 0..31: row within 32-row pass
    const int g_lin = tid & 7;               // linear dest granule (8 shorts)
    const int g_src = g_lin ^ (sr & 7);      // pre-swizzled source granule
    const int swz = lcol & 7;                // read-side XOR (= row&7 of read row)

    for (int k0 = 0; k0 < 1024; k0 += 64) {
        __syncthreads();
#pragma unroll
        for (int p = 0; p < 4; p++) {
            glds16(Xb + (size_t)(m0 + p * 32 + sr) * 1024 + k0 + g_src * 8,
                   &As[(p * 32 + sr) * 64 + g_lin * 8]);
            glds16(Wt + (size_t)(n0 + p * 32 + sr) * 1024 + k0 + g_src * 8,
                   &Bs[(p * 32 + sr) * 64 + g_lin * 8]);
        }
        __syncthreads();
#pragma unroll
        for (int kk = 0; kk < 2; kk++) {
            bf16x8 a[4], b[4];
#pragma unroll
            for (int i = 0; i < 4; i++)
                a[i] = *(const bf16x8*)(&As[(wrow + 16 * i + lcol) * 64
                                            + ((kk * 4 + quad) ^ swz) * 8]);
#pragma unroll
            for (int j = 0; j < 4; j++)
                b[j] = *(const bf16x8*)(&Bs[(wcol + 16 * j + lcol) * 64
                                            + ((kk * 4 + quad) ^ swz) * 8]);
#pragma unroll
            for (int i = 0; i < 4; i++)
#pragma unroll
                for (int j = 0; j < 4; j++)
                    acc[i][j] = __builtin_amdgcn_mfma_f32_16x16x32_bf16(
                        a[i], b[j], acc[i][j], 0, 0, 0);
        }
    }
    __syncthreads();   // all ds_reads done before reusing Sh as epilogue buf

    // ---- epilogue: stage 128x128 tile into Es in blob order, copy out ----
    short* Es = Sh;                          // 32 KB = 2 blobs of 16 KB
    const int which = n0 >> 10;              // 0=Q 1=K 2=V (tile-uniform)
    const int h0 = (n0 & 1023) >> 6;         // first head in tile
    const int bb = m0 >> 10;
    const int sl0 = m0 & 1023;
    const int kt = sl0 >> 7;

#pragma unroll
    for (int j = 0; j < 4; j++) {
        int colt = wcol + 16 * j + lcol;     // 0..127
        float bias = bq[n0 + colt];
        int g = colt >> 6, e = colt & 63;
#pragma unroll
        for (int i = 0; i < 4; i++) {
#pragma unroll
            for (int reg = 0; reg < 4; reg++) {
                int ls = wrow + 16 * i + quad * 4 + reg;   // 0..127
                unsigned short v = f2b(acc[i][j][reg] + bias);
                int off;
                if (which == 0)
                    off = ls * 64 + e;
                else if (which == 1)
                    off = (e >> 5) * 4096 + (ls >> 4) * 512
                        + (((e >> 3) & 3) * 16 + (ls & 15)) * 8 + (e & 7);
                else
                    off = (ls >> 5) * 2048 + (e >> 4) * 512
                        + (((ls >> 3) & 3) * 16 + (e & 15)) * 8 + (ls & 7);
                Es[g * 8192 + off] = (short)v;
            }
        }
    }
    __syncthreads();

    // copy out 32 KB: 8 passes of 256 x b128 (two 16 KB head-blobs)
#pragma unroll
    for (int rd = 0; rd < 8; rd++) {
        int fl = rd * 2048 + tid * 8;
        int g = fl >> 13, off = fl & 8191;
        bf16x8 val = *(const bf16x8*)(&Es[fl]);
        int bh = bb * 16 + h0 + g;
        if (which == 0)
            *(bf16x8*)(Qb + ((size_t)bh * 1024 + sl0) * 64 + off) = val;
        else if (which == 1)
            *(bf16x8*)(Kf + ((size_t)bh * 8 + kt) * 8192 + off) = val;
        else
            *(bf16x8*)(Vf + ((size_t)bh * 8 + kt) * 8192 + off) = val;
    }
}

// ---------------------------------------------------------------------------
// K2: causal flash attention — EQUAL-WORK blocks + SWAPPED-OPERAND QK^T
// + s_setprio. Grid (128, 8): XCD = bh%8 -> each XCD owns 16 heads, K/V
// footprint 4 MB = one L2 (round-11 verified PASS).
// ---------------------------------------------------------------------------
__global__ __launch_bounds__(256, 4) void attn_kern(
    const unsigned short* __restrict__ Qb,
    const unsigned short* __restrict__ Kf,
    const unsigned short* __restrict__ Vf,
    unsigned short* __restrict__ Ob)
{
    __shared__ __align__(16) short Ps[64 * 136];    // 17.4 KB, wave-private slices

    const int bh = blockIdx.x;                      // 0..127  (XCD = bh%8)
    const int xb = blockIdx.y;                      // 0..7
    const int pr = xb >> 1;                         // pair 0..3
    const int hf = xb & 1;                          // half-strip 0..1
    const unsigned short* Qp = Qb + (size_t)bh * 65536;
    const unsigned short* Kp = Kf + (size_t)bh * 65536;
    const unsigned short* Vp = Vf + (size_t)bh * 65536;

    const int tid = threadIdx.x;
    const int wave = tid >> 6, lane = tid & 63;
    const int quad = lane >> 4, lcol = lane & 15;
    const int hw4 = hf * 4 + wave;                  // 0..7: 16-row strip in tile
    const int qloc = hw4 * 16 + lcol;               // lane's q within its tile

    const float sc2 = 0.0450711882f;  // log2(e)/32  (scale folded into exp2)
    const int b = bh >> 4, h = bh & 15;

    for (int pass = 0; pass < 2; pass++) {
        const int qt = pass ? (7 - pr) : pr;        // q-tile index 0..7
        const int q0 = qt * 128 + hf * 64 + wave * 16;  // wave's first q row

        // Q fragments (B-operand: q=lane&15, k=quad*8+t)
        bf16x8 qa[2];
#pragma unroll
        for (int kk = 0; kk < 2; kk++)
            qa[kk] = *(const bf16x8*)(Qp + (size_t)(q0 + lcol) * 64
                                      + kk * 32 + quad * 8);

        f32x4 o_acc[4];
#pragma unroll
        for (int jo = 0; jo < 4; jo++) o_acc[jo] = (f32x4){0.f, 0.f, 0.f, 0.f};
        float l_loc = 0.f;

        for (int kt = 0; kt <= qt; kt++) {
            const bool diag = (kt == qt);
            const int jmax = diag ? hw4 : 7;        // max live 16-key tile
            const int kk2max = diag ? (hw4 >> 1) : 3;

            // S^T = K Q^T : lane holds S^T[key=16j+quad*4+reg][q=lcol]
            f32x4 scT[8];
#pragma unroll
            for (int j = 0; j < 8; j++) scT[j] = (f32x4){0.f, 0.f, 0.f, 0.f};
#pragma unroll
            for (int kk = 0; kk < 2; kk++) {
                bf16x8 kb[8];
#pragma unroll
                for (int j = 0; j < 8; j++)
                    if (j <= jmax)
                        kb[j] = *(const bf16x8*)(Kp
                            + ((size_t)((kt * 2 + kk) * 8 + j) << 9) + lane * 8);
                __builtin_amdgcn_s_setprio(1);
#pragma unroll
                for (int j = 0; j < 8; j++)
                    if (j <= jmax)
                        scT[j] = __builtin_amdgcn_mfma_f32_16x16x32_bf16(
                            kb[j], qa[kk], scT[j], 0, 0, 0);
                __builtin_amdgcn_s_setprio(0);
            }

            // max-free softmax; packed b64 store to Ps[q][key]
#pragma unroll
            for (int j = 0; j < 8; j++) {
                if (j <= jmax) {
                    float pv[4];
#pragma unroll
                    for (int r = 0; r < 4; r++) {
                        float p = exp2f(scT[j][r] * sc2);
                        if (diag && (16 * j + quad * 4 + r) > qloc) p = 0.f;
                        l_loc += p;
                        pv[r] = p;
                    }
                    ushort4 pk;
                    pk.x = f2b(pv[0]); pk.y = f2b(pv[1]);
                    pk.z = f2b(pv[2]); pk.w = f2b(pv[3]);
                    *(ushort4*)(&Ps[(wave * 16 + lcol) * 136 + 16 * j + quad * 4]) = pk;
                }
            }
            // diag with even jmax: PV's kk2max chunk reads tile jmax+1 -> zero it
            if (diag && !(jmax & 1)) {
                *(ushort4*)(&Ps[(wave * 16 + lcol) * 136 + 16 * (jmax + 1) + quad * 4]) =
                    (ushort4){0, 0, 0, 0};
            }

            // O += P @ V  (pa: A-layout b128 read of own rows; vb: 1 KB loads)
#pragma unroll
            for (int kk2 = 0; kk2 < 4; kk2++) {
                if (kk2 <= kk2max) {
                    bf16x8 pa = *(const bf16x8*)(&Ps[(wave * 16 + lcol) * 136
                                                     + kk2 * 32 + quad * 8]);
                    bf16x8 vb[4];
#pragma unroll
                    for (int jo = 0; jo < 4; jo++)
                        vb[jo] = *(const bf16x8*)(Vp
                            + ((size_t)((kt * 4 + kk2) * 4 + jo) << 9) + lane * 8);
                    __builtin_amdgcn_s_setprio(1);
#pragma unroll
                    for (int jo = 0; jo < 4; jo++)
                        o_acc[jo] = __builtin_amdgcn_mfma_f32_16x16x32_bf16(
                            pa, vb[jo], o_acc[jo], 0, 0, 0);
                    __builtin_amdgcn_s_setprio(0);
                }
            }
        }

        // l: sum the 4 quads (lanes with equal lcol hold the same q)
        l_loc += __shfl_xor(l_loc, 16);
        l_loc += __shfl_xor(l_loc, 32);
        float inv = 1.0f / l_loc;                   // inv for q = q0 + lcol
        float invq[4];
#pragma unroll
        for (int r = 0; r < 4; r++) invq[r] = __shfl(inv, quad * 4 + r);

        // write O -> [B, S, H*hd] bf16  (C-layout: row=q=quad*4+reg, col=d=16jo+lcol)
#pragma unroll
        for (int jo = 0; jo < 4; jo++) {
#pragma unroll
            for (int r = 0; r < 4; r++) {
                int q = q0 + quad * 4 + r;
                Ob[(size_t)(b * 1024 + q) * 1024 + h * 64 + 16 * jo + lcol] =
                    f2b(o_acc[jo][r] * invq[r]);
            }
        }
        l_loc = 0.f;
    }
}

// ---------------------------------------------------------------------------
// K3: out proj. P2[8192,1024](bf16) = O @ Wout + bout + X(fp32 residual)
// 128x128 tile + XOR-swizzled LDS + XCD-chunked remap (round-5 verified).
// XCD owns rows [xcd*1024, (xcd+1)*1024) of P2 -> ln reader is XCD-aligned.
// ---------------------------------------------------------------------------
__global__ __launch_bounds__(256) void out_gemm(
    const unsigned short* __restrict__ O,
    const unsigned short* __restrict__ Wt2,  // [1024][1024] bf16 = Wout^T
    const float* __restrict__ bo,
    const float* __restrict__ X,
    unsigned short* __restrict__ P2)
{
    __shared__ __align__(16) short As[128 * 64];
    __shared__ __align__(16) short Bs[128 * 64];

    // XCD-chunked remap: 512 blocks, 64 per XCD = 8 row-tiles x 8 col-tiles
    const int flat = blockIdx.y * 8 + blockIdx.x;
    const int xcd = flat & 7, local = flat >> 3;
    const int m0 = (xcd * 8 + (local >> 3)) * 128;
    const int n0 = (local & 7) * 128;

    const int tid = threadIdx.x;
    const int wave = tid >> 6, lane = tid & 63;
    const int quad = lane >> 4, lcol = lane & 15;
    const int wrow = (wave >> 1) * 64, wcol = (wave & 1) * 64;

    f32x4 acc[4][4];
#pragma unroll
    for (int i = 0; i < 4; i++)
#pragma unroll
        for (int j = 0; j < 4; j++) acc[i][j] = (f32x4){0.f, 0.f, 0.f, 0.f};

    const int sr = tid >> 3;                 // 0..31
    const int g_lin = tid & 7;
    const int g_src = g_lin ^ (sr & 7);
    const int swz = lcol & 7;

    for (int k0 = 0; k0 < 1024; k0 += 64) {
        __syncthreads();
#pragma unroll
        for (int p = 0; p < 4; p++) {
            glds16(O + (size_t)(m0 + p * 32 + sr) * 1024 + k0 + g_src * 8,
                   &As[(p * 32 + sr) * 64 + g_lin * 8]);
            glds16(Wt2 + (size_t)(n0 + p * 32 + sr) * 1024 + k0 + g_src * 8,
                   &Bs[(p * 32 + sr) * 64 + g_lin * 8]);
        }
        __syncthreads();
#pragma unroll
        for (int kk = 0; kk < 2; kk++) {
            bf16x8 a[4], b[4];
#pragma unroll
            for (int i = 0; i < 4; i++)
                a[i] = *(const bf16x8*)(&As[(wrow + 16 * i + lcol) * 64
                                            + ((kk * 4 + quad) ^ swz) * 8]);
#pragma unroll
            for (int j = 0; j < 4; j++)
                b[j] = *(const bf16x8*)(&Bs[(wcol + 16 * j + lcol) * 64
                                            + ((kk * 4 + quad) ^ swz) * 8]);
#pragma unroll
            for (int i = 0; i < 4; i++)
#pragma unroll
                for (int j = 0; j < 4; j++)
                    acc[i][j] = __builtin_amdgcn_mfma_f32_16x16x32_bf16(
                        a[i], b[j], acc[i][j], 0, 0, 0);
        }
    }

#pragma unroll
    for (int j = 0; j < 4; j++) {
        int c = n0 + wcol + 16 * j + lcol;
        float bias = bo[c];
#pragma unroll
        for (int i = 0; i < 4; i++) {
#pragma unroll
            for (int reg = 0; reg < 4; reg++) {
                int r = m0 + wrow + 16 * i + quad * 4 + reg;
                float v = acc[i][j][reg] + bias + X[(size_t)r * 1024 + c];
                P2[(size_t)r * 1024 + c] = f2b(v);
            }
        }
    }
}

// ---------------------------------------------------------------------------
// K4: LayerNorm — wave-per-row (no LDS, no __syncthreads), 4 rows/block.
// XCD-aligned row mapping: block b handles rows (b%8)*1024 + (b/8)*4 + wave,
// so the reader XCD (= b%8) matches the out_gemm writer XCD (= row/1024)
// -> P2 reads are same-L2 hits instead of cross-XCD misses.
// ---------------------------------------------------------------------------
__global__ __launch_bounds__(256) void ln_kern(
    const unsigned short* __restrict__ P2,
    const float* __restrict__ G,
    const float* __restrict__ Bt,
    float* __restrict__ out)
{
    const int tid = threadIdx.x;
    const int wave = tid >> 6, lane = tid & 63;
    const int row = (blockIdx.x & 7) * 1024 + (blockIdx.x >> 3) * 4 + wave;
    const size_t base = (size_t)row * 1024;

    // lane covers els [lane*8, lane*8+8) and [512+lane*8, 512+lane*8+8)
    float v[16];
    float sum = 0.f, sq = 0.f;
#pragma unroll
    for (int c = 0; c < 2; c++) {
        int4 raw = *(const int4*)(P2 + base + c * 512 + lane * 8);
        const unsigned short* u = (const unsigned short*)&raw;
#pragma unroll
        for (int t = 0; t < 8; t++) {
            float f = b2f(u[t]);
            v[c * 8 + t] = f;
            sum += f;
            sq += f * f;
        }
    }
#pragma unroll
    for (int m = 1; m < 64; m <<= 1) {
        sum += __shfl_xor(sum, m);
        sq += __shfl_xor(sq, m);
    }

    float mean = sum * (1.0f / 1024.0f);
    float var = fmaxf(sq * (1.0f / 1024.0f) - mean * mean, 0.0f);
    float rstd = rsqrtf(var + 1e-5f);

#pragma unroll
    for (int c = 0; c < 2; c++) {
        int e0 = c * 512 + lane * 8;
        float4 g0 = *(const float4*)(G + e0);
        float4 g1 = *(const float4*)(G + e0 + 4);
        float4 b0 = *(const float4*)(Bt + e0);
        float4 b1 = *(const float4*)(Bt + e0 + 4);
        float4 o0, o1;
        o0.x = (v[c * 8 + 0] - mean) * rstd * g0.x + b0.x;
        o0.y = (v[c * 8 + 1] - mean) * rstd * g0.y + b0.y;
        o0.z = (v[c * 8 + 2] - mean) * rstd * g0.z + b0.z;
        o0.w = (v[c * 8 + 3] - mean) * rstd * g0.w + b0.w;
        o1.x = (v[c * 8 + 4] - mean) * rstd * g1.x + b1.x;
        o1.y = (v[c * 8 + 5] - mean) * rstd * g1.y + b1.y;
        o1.z = (v[c * 8 + 6] - mean) * rstd * g1.z + b1.z;
        o1.w = (v[c * 8 + 7] - mean) * rstd * g1.w + b1.w;
        *(float4*)(out + base + e0) = o0;
        *(float4*)(out + base + e0 + 4) = o1;
    }
}

// ---------------------------------------------------------------------------
// Buffer plan:
//   d_out (32 MB): Qb bf16 @0, Ob bf16 @16M; final fp32 result overwrites.
//   d_ws  (56 MB): Kf @0, Vf @16M, Wt2 @32M (2M), Xb @34M (16M), Wt @50M (6M)
//   P2 bf16 @34M aliases Xb (dead after qkv_gemm).
// ---------------------------------------------------------------------------
extern "C" void kernel_launch(void* const* d_in, const int* in_sizes, int n_in,
                              void* d_out, int out_size, void* d_ws, size_t ws_size,
                              hipStream_t stream) {
    const float* x    = (const float*)d_in[0];
    const float* Wqkv = (const float*)d_in[1];
    const float* bqkv = (const float*)d_in[2];
    const float* Wout = (const float*)d_in[3];
    const float* bout = (const float*)d_in[4];
    const float* gam  = (const float*)d_in[5];
    const float* bet  = (const float*)d_in[6];
    float* out = (float*)d_out;

    char* ws = (char*)d_ws;
    const size_t MB = (size_t)1024 * 1024;

    unsigned short* Qb  = (unsigned short*)d_out;
    unsigned short* Ob  = (unsigned short*)d_out + 8388608;
    unsigned short* Kf  = (unsigned short*)(ws);
    unsigned short* Vf  = (unsigned short*)(ws + 16 * MB);
    unsigned short* Wt2 = (unsigned short*)(ws + 32 * MB);
    unsigned short* Xb  = (unsigned short*)(ws + 34 * MB);
    unsigned short* Wt  = (unsigned short*)(ws + 50 * MB);
    unsigned short* P2  = (unsigned short*)(ws + 34 * MB);   // alias Xb

    prep_kern<<<5120, 256, 0, stream>>>(x, Xb, Wqkv, Wt, Wout, Wt2);
    qkv_gemm<<<dim3(24, 64), 256, 0, stream>>>(Xb, Wt, bqkv, Qb, Kf, Vf);
    attn_kern<<<dim3(128, 8), 256, 0, stream>>>(Qb, Kf, Vf, Ob);
    out_gemm<<<dim3(8, 64), 256, 0, stream>>>(Ob, Wt2, bout, x, P2);
    ln_kern<<<2048, 256, 0, stream>>>(P2, gam, bet, out);
}